// Round 1
// baseline (490.400 us; speedup 1.0000x reference)
//
#include <hip/hip_runtime.h>

// Problem constants
#define TT   512
#define HH   257
#define WW   257
#define HWSZ (HH*WW)        // 66049
#define IMG2 (2*HWSZ)       // stride between time steps in `output` (2 channels)
#define NPIX (255*255)      // 65025 interior pixels
#define BM   128            // time-rows per block
#define BP   128            // pixels per block
#define BK   16             // k-chunk

// w[j] = (j+1)^0.5 - j^0.5  (f32, same as the jnp reference)
__device__ __forceinline__ float wf(int j) {
    return sqrtf((float)(j + 1)) - sqrtf((float)j);
}

// M[i][k] entry, computed on the fly.
__device__ __forceinline__ float mcoef(int i, int k) {
    if (i == 0 || k > i) return 0.f;
    if (k == i) return 1.f;
    if (k == 0) return -wf(i - 1);
    int d = i - k;                 // 1..510
    return wf(d) - wf(d - 1);      // = -dvec[d] = -(w[d-1]-w[d])
}

__global__ __launch_bounds__(256)
void fdm_loss_kernel(const float* __restrict__ uin,   // (T,2,H,W), channel 0 = u
                     const float* __restrict__ f1,    // (T,1,H,W)
                     const float* __restrict__ lapk,  // 9 coeffs
                     float* __restrict__ d_out)
{
    __shared__ __align__(16) float u_lds[BK][BP];
    __shared__ __align__(16) float m_lds[BK][BM];
    __shared__ float red[4];

    const int tid  = threadIdx.x;
    const int tc   = tid & 15;    // pixel group 0..15
    const int tr   = tid >> 4;    // row group   0..15
    const int pix0 = blockIdx.x * BP;
    const int row0 = blockIdx.y * BM;

    float acc[8][8];
    #pragma unroll
    for (int a = 0; a < 8; ++a)
        #pragma unroll
        for (int b = 0; b < 8; ++b) acc[a][b] = 0.f;

    const int kmax = row0 + BM;   // triangular bound (<= 512)

    for (int kc = 0; kc < kmax; kc += BK) {
        // ---- stage M coefficients: m_lds[kk][m] = M[row0+m][kc+kk]
        #pragma unroll
        for (int j = 0; j < (BK * BM) / 256; ++j) {
            int l  = tid + j * 256;
            int kk = l >> 7;          // /128
            int m  = l & 127;
            m_lds[kk][m] = mcoef(row0 + m, kc + kk);
        }
        // ---- stage u chunk: u_lds[kk][c] = u[kc+kk][interior pixel pix0+c]
        #pragma unroll
        for (int j = 0; j < (BK * BP) / 256; ++j) {
            int l  = tid + j * 256;
            int kk = l >> 7;
            int c  = l & 127;
            int p  = pix0 + c; if (p >= NPIX) p = NPIX - 1;
            int y  = 1 + p / 255;
            int x  = 1 + p - (p / 255) * 255;
            u_lds[kk][c] = uin[(size_t)(kc + kk) * IMG2 + y * WW + x];
        }
        __syncthreads();

        #pragma unroll
        for (int kk = 0; kk < BK; ++kk) {
            const float4* ap = reinterpret_cast<const float4*>(&m_lds[kk][tr * 8]);
            const float4* bp = reinterpret_cast<const float4*>(&u_lds[kk][tc * 8]);
            float4 a0 = ap[0], a1 = ap[1];
            float4 b0 = bp[0], b1 = bp[1];
            float am[8] = {a0.x, a0.y, a0.z, a0.w, a1.x, a1.y, a1.z, a1.w};
            float bm[8] = {b0.x, b0.y, b0.z, b0.w, b1.x, b1.y, b1.z, b1.w};
            #pragma unroll
            for (int mi = 0; mi < 8; ++mi)
                #pragma unroll
                for (int pj = 0; pj < 8; ++pj)
                    acc[mi][pj] = fmaf(am[mi], bm[pj], acc[mi][pj]);
        }
        __syncthreads();
    }

    // ---- epilogue: res = scale*D + u - (kappa/dx^2)*lap - f1 ; accumulate res^2
    const float scale = 3.5682482323055424f;     // DT^-0.5 / gamma(1.5)
    const float kd    = 163.84f;                 // KAPPA / DX^2
    const float k00 = lapk[0], k01 = lapk[1], k02 = lapk[2];
    const float k10 = lapk[3], k11 = lapk[4], k12 = lapk[5];
    const float k20 = lapk[6], k21 = lapk[7], k22 = lapk[8];

    float lsum = 0.f;
    #pragma unroll
    for (int mi = 0; mi < 8; ++mi) {
        int t = row0 + tr * 8 + mi;
        const float* ub = uin + (size_t)t * IMG2;
        const float* fb = f1  + (size_t)t * HWSZ;
        #pragma unroll
        for (int pj = 0; pj < 8; ++pj) {
            int p = pix0 + tc * 8 + pj;
            if (p >= NPIX) continue;
            int y = 1 + p / 255;
            int x = 1 + p - (p / 255) * 255;
            const float* uc = ub + y * WW + x;
            float lap = k00 * uc[-WW - 1] + k01 * uc[-WW] + k02 * uc[-WW + 1]
                      + k10 * uc[-1]      + k11 * uc[0]   + k12 * uc[1]
                      + k20 * uc[ WW - 1] + k21 * uc[ WW] + k22 * uc[ WW + 1];
            float res = scale * acc[mi][pj] + uc[0] - kd * lap - fb[y * WW + x];
            lsum += res * res;
        }
    }

    // ---- reduce to scalar
    #pragma unroll
    for (int off = 32; off > 0; off >>= 1)
        lsum += __shfl_down(lsum, off, 64);
    int wave = tid >> 6, lane = tid & 63;
    if (lane == 0) red[wave] = lsum;
    __syncthreads();
    if (tid == 0) {
        float tot = red[0] + red[1] + red[2] + red[3];
        atomicAdd(d_out, tot * (1.0f / 33292800.0f));   // / (512*255*255)
    }
}

extern "C" void kernel_launch(void* const* d_in, const int* in_sizes, int n_in,
                              void* d_out, int out_size, void* d_ws, size_t ws_size,
                              hipStream_t stream)
{
    const float* uin  = (const float*)d_in[0];
    const float* f1   = (const float*)d_in[1];
    const float* lapk = (const float*)d_in[2];
    float* out = (float*)d_out;

    hipMemsetAsync(out, 0, sizeof(float), stream);

    dim3 grid((NPIX + BP - 1) / BP, TT / BM);   // (509, 4)
    fdm_loss_kernel<<<grid, 256, 0, stream>>>(uin, f1, lapk, out);
}

// Round 2
// 283.141 us; speedup vs baseline: 1.7320x; 1.7320x over previous
//
#include <hip/hip_runtime.h>

#define TT    512
#define WW    257
#define HWSZ  (WW*WW)          // 66049
#define IMG2  (2*HWSZ)         // time stride in `output` (2 channels)
#define SCALE 3.5682482323055424f   // DT^-0.5 / gamma(1.5)
#define KD    163.84f               // KAPPA / DX^2

typedef short bf16x8 __attribute__((ext_vector_type(8)));
typedef float f32x4  __attribute__((ext_vector_type(4)));

__device__ __forceinline__ float wf(int j) {
    return sqrtf((float)(j + 1)) - sqrtf((float)j);
}
// M[i][k] of the L1 fractional-derivative weight matrix
__device__ __forceinline__ float mcoef(int i, int k) {
    if (i == 0 || k > i) return 0.f;
    if (k == i) return 1.f;
    if (k == 0) return -wf(i - 1);
    int d = i - k;
    return wf(d) - wf(d - 1);
}
// f32 -> bf16 RNE
__device__ __forceinline__ unsigned short f2b(float f) {
    unsigned u = __float_as_uint(f);
    return (unsigned short)((u + 0x7FFFu + ((u >> 16) & 1u)) >> 16);
}

// ---- pre-kernel: materialize M as bf16[512][512] in workspace
__global__ void build_m(unsigned short* __restrict__ M) {
    int i = blockIdx.x;
    for (int k = threadIdx.x; k < TT; k += 256)
        M[i * TT + k] = f2b(mcoef(i, k));
}

// ---- fused MFMA GEMM + stencil + loss
// grid (8, 255): x-tile (32 px) x image row y. 512 threads = 8 waves.
// wave w owns output times i in [64w, 64w+64), all 32 pixels; triangular k-loop.
__global__ __launch_bounds__(512)
void fdm_mfma(const float* __restrict__ uin, const float* __restrict__ f1,
              const float* __restrict__ lapk, const unsigned short* __restrict__ Mb,
              float* __restrict__ d_out)
{
    __shared__ float red[8];
    const int tid  = threadIdx.x;
    const int w    = tid >> 6;
    const int lane = tid & 63;
    const int lr   = lane & 15;     // A row (pixel) low / B col (time) low
    const int lg   = lane >> 4;     // k-slot group

    const int y  = 1 + blockIdx.y;          // interior image row
    const int x0 = 1 + blockIdx.x * 32;     // first interior x of tile
    const int i0 = w * 64;                  // wave's first output time

    f32x4 acc[2][4];
    #pragma unroll
    for (int a = 0; a < 2; ++a)
        #pragma unroll
        for (int b = 0; b < 4; ++b) acc[a][b] = (f32x4)0.f;

    const size_t urow = (size_t)y * WW;
    const int pxA0 = x0 + lr;        // A-operand pixel columns (mi=0 / mi=1)
    const int pxA1 = x0 + 16 + lr;
    const int kend = (2 * w + 2) * 32;      // k <= 64w+63 (triangular)

    for (int kc = 0; kc < kend; kc += 32) {
        const int kbase = kc + 8 * lg;      // my k-slot start (kmap: k = kbase + j)

        // B fragments: M^T — lane holds M[i][kbase..kbase+7], one 16B load
        bf16x8 bfr[4];
        #pragma unroll
        for (int nj = 0; nj < 4; ++nj) {
            int i = i0 + nj * 16 + lr;
            bfr[nj] = *(const bf16x8*)(Mb + (size_t)i * TT + kbase);
        }
        // A fragments: u^T — lane holds u[kbase+j][y][px], 8 coalesced f32 loads
        #pragma unroll
        for (int mi = 0; mi < 2; ++mi) {
            const float* up = uin + (size_t)kbase * IMG2 + urow + (mi ? pxA1 : pxA0);
            float uv[8];
            #pragma unroll
            for (int j = 0; j < 8; ++j) uv[j] = up[(size_t)j * IMG2];
            bf16x8 afr;
            #pragma unroll
            for (int j = 0; j < 8; ++j) afr[j] = (short)f2b(uv[j]);
            #pragma unroll
            for (int nj = 0; nj < 4; ++nj)
                acc[mi][nj] = __builtin_amdgcn_mfma_f32_16x16x32_bf16(
                                  afr, bfr[nj], acc[mi][nj], 0, 0, 0);
        }
    }

    // ---- epilogue: res = SCALE*D + u - KD*lap - f1 ; accumulate res^2
    const float k00 = lapk[0], k01 = lapk[1], k02 = lapk[2];
    const float k10 = lapk[3], k11 = lapk[4], k12 = lapk[5];
    const float k20 = lapk[6], k21 = lapk[7], k22 = lapk[8];

    float lsum = 0.f;
    #pragma unroll
    for (int mi = 0; mi < 2; ++mi) {
        const int pxb = x0 + mi * 16 + lg * 4;   // lane's 4 consecutive pixels
        #pragma unroll
        for (int nj = 0; nj < 4; ++nj) {
            const int t = i0 + nj * 16 + lr;     // lane's output time
            const float* uc = uin + (size_t)t * IMG2 + urow + pxb;
            const float* fb = f1  + (size_t)t * HWSZ + urow + pxb;
            float um[3][6];
            #pragma unroll
            for (int rr = 0; rr < 3; ++rr) {
                const float* rp = uc + (rr - 1) * WW - 1;
                #pragma unroll
                for (int c = 0; c < 6; ++c) um[rr][c] = rp[c];
            }
            f32x4 a = acc[mi][nj];
            #pragma unroll
            for (int r = 0; r < 4; ++r) {
                float lap = k00 * um[0][r] + k01 * um[0][r + 1] + k02 * um[0][r + 2]
                          + k10 * um[1][r] + k11 * um[1][r + 1] + k12 * um[1][r + 2]
                          + k20 * um[2][r] + k21 * um[2][r + 1] + k22 * um[2][r + 2];
                float res = SCALE * a[r] + um[1][r + 1] - KD * lap - fb[r];
                if (pxb + r <= 255) lsum += res * res;
            }
        }
    }

    // ---- reduce: wave shfl -> LDS -> one atomic per block
    #pragma unroll
    for (int off = 32; off > 0; off >>= 1)
        lsum += __shfl_down(lsum, off, 64);
    if (lane == 0) red[w] = lsum;
    __syncthreads();
    if (tid == 0) {
        float tot = 0.f;
        #pragma unroll
        for (int q = 0; q < 8; ++q) tot += red[q];
        atomicAdd(d_out, tot * (1.0f / 33292800.0f));
    }
}

extern "C" void kernel_launch(void* const* d_in, const int* in_sizes, int n_in,
                              void* d_out, int out_size, void* d_ws, size_t ws_size,
                              hipStream_t stream)
{
    const float* uin  = (const float*)d_in[0];
    const float* f1   = (const float*)d_in[1];
    const float* lapk = (const float*)d_in[2];
    float* out = (float*)d_out;
    unsigned short* Mb = (unsigned short*)d_ws;   // 512*512*2 = 512 KB

    hipMemsetAsync(out, 0, sizeof(float), stream);
    build_m<<<dim3(TT), 256, 0, stream>>>(Mb);

    dim3 grid(8, 255);
    fdm_mfma<<<grid, 512, 0, stream>>>(uin, f1, lapk, Mb, out);
}